// Round 1
// baseline (8474.738 us; speedup 1.0000x reference)
//
#include <hip/hip_runtime.h>
#include <hip/hip_fp16.h>

#define TSEQ 1024
#define NBATCH 256
#define HD 256
#define ID 128
#define ODIM 128
#define ROWP 264  // padded LDS row length (f16 elems): 256 + 8 to break bank alignment

typedef _Float16 f16;
typedef _Float16 f16x8 __attribute__((ext_vector_type(8)));
typedef float f32x4 __attribute__((ext_vector_type(4)));

// ---------------------------------------------------------------------------
// K0: pack recurrent + input weights into fp16, row order n' = j*256 + g*64 + uu
//     (j = hidden slice 0..3, g = gate 0..3 [g,i,f,o], uu = unit within slice)
// ---------------------------------------------------------------------------
__global__ void pack_weights(
    const float* __restrict__ Wgh, const float* __restrict__ Wih,
    const float* __restrict__ Wfh, const float* __restrict__ Woh,
    const float* __restrict__ Wgx, const float* __restrict__ Wix,
    const float* __restrict__ Wfx, const float* __restrict__ Wox,
    const float* __restrict__ bgx, const float* __restrict__ bix,
    const float* __restrict__ bfx, const float* __restrict__ box,
    f16* __restrict__ Whcat, f16* __restrict__ Wxcat, float* __restrict__ bcat)
{
    const int np = blockIdx.x;            // 0..1023  (row n')
    const int g  = (np >> 6) & 3;         // gate
    const int j  = np >> 8;               // hidden slice
    const int uu = np & 63;
    const int u  = j * 64 + uu;           // global hidden unit
    const float* Wh = (g == 0) ? Wgh : (g == 1) ? Wih : (g == 2) ? Wfh : Woh;
    const float* Wx = (g == 0) ? Wgx : (g == 1) ? Wix : (g == 2) ? Wfx : Wox;
    const float* bx = (g == 0) ? bgx : (g == 1) ? bix : (g == 2) ? bfx : box;
    const int k = threadIdx.x;            // 0..255
    Whcat[np * 256 + k] = (f16)Wh[u * 256 + k];
    if (k < ID) Wxcat[np * ID + k] = (f16)Wx[u * ID + k];
    if (k == 0) bcat[np] = bx[u];
}

// ---------------------------------------------------------------------------
// K2: persistent fused recurrence.
// Grid: 64 WGs x 256 threads. WG = (grp 0..15 [batch tile of 16], j 0..3 [hidden slice]).
// Wh slice (256 rows x 256 k) and Wx slice (256 rows x 128 k) live in registers
// as MFMA B-fragments. Groups of 4 WGs exchange h each step through global
// memory with agent-scope atomics + monotone per-wave release counters.
// MFMA 16x16x32 f16 layouts (per guide):
//   A[m = lane&15][k = (lane>>4)*8 + e]
//   B[k = (lane>>4)*8 + e][n = lane&15]
//   D[m = (lane>>4)*4 + r][n = lane&15]
// ---------------------------------------------------------------------------
__global__ __launch_bounds__(256, 1) void lstm_rec(
    const float* __restrict__ x,
    const f16* __restrict__ Whcat,
    const f16* __restrict__ Wxcat,
    const float* __restrict__ bcat,
    f16* __restrict__ hbuf,     // [2][NBATCH][HD] fp16, parity double-buffer
    float* __restrict__ hT,     // [NBATCH][HD] fp32 final h
    int* __restrict__ flags)    // [16][4] monotone wave-arrival counters
{
    __shared__ f16 h_lds[16 * ROWP];

    const int tid  = threadIdx.x;
    const int lane = tid & 63;
    const int w    = tid >> 6;      // wave 0..3  -> owns units [w*16, w*16+16)
    const int q    = lane >> 4;     // quad
    const int n    = lane & 15;
    const int bid  = blockIdx.x;
    const int grp  = bid >> 2;      // batch-tile group 0..15
    const int j    = bid & 3;       // hidden slice
    const int b0   = grp * 16;

    // ---- persistent weight fragments ----
    f16x8 wh[4][8];   // [gate][kk] recurrent, K=256 -> 8 steps of 32
    f16x8 wx[4][4];   // [gate][k4] input,     K=128 -> 4 steps of 32
    float bias[4];
#pragma unroll
    for (int g = 0; g < 4; ++g) {
        const int row = j * 256 + g * 64 + w * 16 + n;   // B-fragment n-index = lane&15
        bias[g] = bcat[row];
#pragma unroll
        for (int kk = 0; kk < 8; ++kk)
            wh[g][kk] = *(const f16x8*)&Whcat[row * 256 + kk * 32 + q * 8];
#pragma unroll
        for (int k4 = 0; k4 < 4; ++k4)
            wx[g][k4] = *(const f16x8*)&Wxcat[row * ID + k4 * 32 + q * 8];
    }

    float c[4] = {0.f, 0.f, 0.f, 0.f};          // cell state: (b = b0+q*4+r, unit uglob)
    const int uglob = j * 64 + w * 16 + n;

    const int sb = tid >> 4;            // stage-in: batch row 0..15
    const int su = (tid & 15) * 16;     // stage-in: unit offset

    for (int t = 0; t < TSEQ; ++t) {
        // ---- issue x loads early (fp32, overlaps the spin) ----
        float4 xr[8];
        {
            const float* xp = &x[((size_t)(b0 + n) * TSEQ + t) * ID];
#pragma unroll
            for (int k4 = 0; k4 < 4; ++k4) {
                xr[k4 * 2]     = *(const float4*)&xp[k4 * 32 + q * 8];
                xr[k4 * 2 + 1] = *(const float4*)&xp[k4 * 32 + q * 8 + 4];
            }
        }

        if (t > 0) {
            // wait for all 4 producers of h(t-1): each posted 4 wave-arrivals/step
            if (tid < 4) {
                while (__hip_atomic_load(&flags[grp * 4 + tid], __ATOMIC_ACQUIRE,
                                         __HIP_MEMORY_SCOPE_AGENT) < 4 * t)
                    __builtin_amdgcn_s_sleep(2);
            }
            __syncthreads();
            // stage h(t-1) -> LDS (agent-scope loads bypass stale L2)
            const unsigned long long* gp = (const unsigned long long*)
                &hbuf[(size_t)(((t - 1) & 1) * NBATCH + b0 + sb) * HD + su];
            unsigned long long v[4];
#pragma unroll
            for (int i2 = 0; i2 < 4; ++i2)
                v[i2] = __hip_atomic_load(gp + i2, __ATOMIC_RELAXED,
                                          __HIP_MEMORY_SCOPE_AGENT);
            unsigned long long* lp = (unsigned long long*)&h_lds[sb * ROWP + su];
#pragma unroll
            for (int i2 = 0; i2 < 4; ++i2) lp[i2] = v[i2];
            __syncthreads();
        }

        // ---- preacts: bias + x-projection + recurrent projection ----
        f32x4 acc[4];
#pragma unroll
        for (int g = 0; g < 4; ++g) {
            f32x4 av = {bias[g], bias[g], bias[g], bias[g]};
            acc[g] = av;
        }

#pragma unroll
        for (int k4 = 0; k4 < 4; ++k4) {
            f16x8 xa;
            const float* f0 = (const float*)&xr[k4 * 2];
            const float* f1 = (const float*)&xr[k4 * 2 + 1];
#pragma unroll
            for (int e = 0; e < 4; ++e) {
                xa[e]     = (f16)f0[e];
                xa[4 + e] = (f16)f1[e];
            }
#pragma unroll
            for (int g = 0; g < 4; ++g)
                acc[g] = __builtin_amdgcn_mfma_f32_16x16x32_f16(xa, wx[g][k4], acc[g], 0, 0, 0);
        }

        if (t > 0) {
#pragma unroll
            for (int kk = 0; kk < 8; ++kk) {
                f16x8 ha = *(const f16x8*)&h_lds[n * ROWP + kk * 32 + q * 8];
#pragma unroll
                for (int g = 0; g < 4; ++g)
                    acc[g] = __builtin_amdgcn_mfma_f32_16x16x32_f16(ha, wh[g][kk], acc[g], 0, 0, 0);
            }
        }

        // ---- gates, cell/hidden update, publish h ----
#pragma unroll
        for (int r = 0; r < 4; ++r) {
            const float gp_ = acc[0][r], ip_ = acc[1][r], fp_ = acc[2][r], op_ = acc[3][r];
            const float gg = 1.f - 2.f / (1.f + __expf(2.f * gp_));
            const float ii = 1.f / (1.f + __expf(-ip_));
            const float ff = 1.f / (1.f + __expf(-fp_));
            const float oo = 1.f / (1.f + __expf(-op_));
            c[r] = gg * ii + c[r] * ff;
            const float hh = (1.f - 2.f / (1.f + __expf(2.f * c[r]))) * oo;
            const int b = b0 + q * 4 + r;
            union { _Float16 f; unsigned short s; } cv;
            cv.f = (_Float16)hh;
            __hip_atomic_store((unsigned short*)&hbuf[(size_t)((t & 1) * NBATCH + b) * HD + uglob],
                               cv.s, __ATOMIC_RELAXED, __HIP_MEMORY_SCOPE_AGENT);
            if (t == TSEQ - 1) hT[(size_t)b * HD + uglob] = hh;
        }

        if (t < TSEQ - 1) {
            // per-wave release: the release RMW drains this wave's vmcnt, so all
            // 64 lanes' h stores are at the coherence point before the count bumps.
            if (lane == 0)
                __hip_atomic_fetch_add(&flags[grp * 4 + j], 1, __ATOMIC_RELEASE,
                                       __HIP_MEMORY_SCOPE_AGENT);
        }
    }
}

// ---------------------------------------------------------------------------
// K3: out[b][o] = sum_u hT[b][u] * Wp[o][u] + bp[o]   (fp32)
// ---------------------------------------------------------------------------
__global__ void out_proj(const float* __restrict__ hT, const float* __restrict__ Wp,
                         const float* __restrict__ bp, float* __restrict__ out)
{
    const int b = blockIdx.x;       // 0..255
    const int o = threadIdx.x;      // 0..127
    __shared__ float hrow[HD];
    for (int u = threadIdx.x; u < HD; u += ODIM) hrow[u] = hT[b * HD + u];
    __syncthreads();
    float s = bp[o];
    const float* wr = &Wp[o * HD];
#pragma unroll 8
    for (int u = 0; u < HD; ++u) s += hrow[u] * wr[u];
    out[b * ODIM + o] = s;
}

// ---------------------------------------------------------------------------
extern "C" void kernel_launch(void* const* d_in, const int* in_sizes, int n_in,
                              void* d_out, int out_size, void* d_ws, size_t ws_size,
                              hipStream_t stream) {
    const float* x   = (const float*)d_in[0];
    const float* Wgx = (const float*)d_in[1];
    const float* bgx = (const float*)d_in[2];
    const float* Wgh = (const float*)d_in[3];
    const float* Wix = (const float*)d_in[4];
    const float* bix = (const float*)d_in[5];
    const float* Wih = (const float*)d_in[6];
    const float* Wfx = (const float*)d_in[7];
    const float* bfx = (const float*)d_in[8];
    const float* Wfh = (const float*)d_in[9];
    const float* Wox = (const float*)d_in[10];
    const float* box = (const float*)d_in[11];
    const float* Woh = (const float*)d_in[12];
    const float* Wp  = (const float*)d_in[13];
    const float* bp  = (const float*)d_in[14];
    float* out = (float*)d_out;

    char* ws = (char*)d_ws;
    f16*   Whcat = (f16*)(ws);                         // 1024*256*2   = 524288
    f16*   Wxcat = (f16*)(ws + 524288);                // 1024*128*2   = 262144
    float* bcat  = (float*)(ws + 786432);              // 1024*4       = 4096
    f16*   hbuf  = (f16*)(ws + 790528);                // 2*256*256*2  = 262144
    float* hT    = (float*)(ws + 1052672);             // 256*256*4    = 262144
    int*   flags = (int*)(ws + 1314816);               // 64*4         = 256

    hipMemsetAsync(flags, 0, 64 * sizeof(int), stream);
    pack_weights<<<1024, 256, 0, stream>>>(Wgh, Wih, Wfh, Woh,
                                           Wgx, Wix, Wfx, Wox,
                                           bgx, bix, bfx, box,
                                           Whcat, Wxcat, bcat);
    lstm_rec<<<64, 256, 0, stream>>>(x, Whcat, Wxcat, bcat, hbuf, hT, flags);
    out_proj<<<NBATCH, ODIM, 0, stream>>>(hT, Wp, bp, out);
}

// Round 2
// 7028.761 us; speedup vs baseline: 1.2057x; 1.2057x over previous
//
#include <hip/hip_runtime.h>
#include <hip/hip_fp16.h>

#define TSEQ 1024
#define NBATCH 256
#define HD 256
#define ID 128
#define ODIM 128

typedef _Float16 f16;
typedef _Float16 f16x8 __attribute__((ext_vector_type(8)));
typedef float f32x4 __attribute__((ext_vector_type(4)));

// ---------------------------------------------------------------------------
// K0: pack recurrent + input weights into fp16, row order n' = j*256 + g*64 + uu
// ---------------------------------------------------------------------------
__global__ void pack_weights(
    const float* __restrict__ Wgh, const float* __restrict__ Wih,
    const float* __restrict__ Wfh, const float* __restrict__ Woh,
    const float* __restrict__ Wgx, const float* __restrict__ Wix,
    const float* __restrict__ Wfx, const float* __restrict__ Wox,
    const float* __restrict__ bgx, const float* __restrict__ bix,
    const float* __restrict__ bfx, const float* __restrict__ box,
    f16* __restrict__ Whcat, f16* __restrict__ Wxcat, float* __restrict__ bcat)
{
    const int np = blockIdx.x;            // 0..1023  (row n')
    const int g  = (np >> 6) & 3;         // gate
    const int j  = np >> 8;               // hidden slice
    const int uu = np & 63;
    const int u  = j * 64 + uu;           // global hidden unit
    const float* Wh = (g == 0) ? Wgh : (g == 1) ? Wih : (g == 2) ? Wfh : Woh;
    const float* Wx = (g == 0) ? Wgx : (g == 1) ? Wix : (g == 2) ? Wfx : Wox;
    const float* bx = (g == 0) ? bgx : (g == 1) ? bix : (g == 2) ? bfx : box;
    const int k = threadIdx.x;            // 0..255
    Whcat[np * 256 + k] = (f16)Wh[u * 256 + k];
    if (k < ID) Wxcat[np * ID + k] = (f16)Wx[u * ID + k];
    if (k == 0) bcat[np] = bx[u];
}

// ---------------------------------------------------------------------------
// K2: persistent fused recurrence.
// 64 WGs x 256 threads. WG = (grp 0..15 [16-batch tile], j 0..3 [64-unit slice]).
// Weights live in registers as MFMA B-fragments. Groups of 4 WGs exchange h
// each step through L3: per-(WG,wave) release-store flag slots, each on its
// own 256B line (no shared-line RMW contention — R1's 8 us/step bug).
// MFMA 16x16x32 f16 layouts:
//   A[m = lane&15][k = (lane>>4)*8 + e]
//   B[n = lane&15][k = (lane>>4)*8 + e]
//   D[m = (lane>>4)*4 + r][n = lane&15]
// ---------------------------------------------------------------------------
__global__ __launch_bounds__(256, 1) void lstm_rec(
    const float* __restrict__ x,
    const f16* __restrict__ Whcat,
    const f16* __restrict__ Wxcat,
    const float* __restrict__ bcat,
    f16* __restrict__ hbuf,     // [2][NBATCH][HD] fp16 parity double-buffer
    float* __restrict__ hT,     // [NBATCH][HD] fp32 final h
    int* __restrict__ flags)    // [256 slots][64 ints]: slot=(grp*16+j*4+w)
{
    const int tid  = threadIdx.x;
    const int lane = tid & 63;
    const int w    = tid >> 6;      // wave 0..3 -> units [w*16, w*16+16)
    const int q    = lane >> 4;
    const int n    = lane & 15;
    const int bid  = blockIdx.x;
    const int grp  = bid >> 2;
    const int j    = bid & 3;
    const int b0   = grp * 16;

    // ---- persistent weight fragments ----
    f16x8 wh[4][8];   // [gate][kk] recurrent, K=256 -> 8 MFMA k-steps
    f16x8 wx[4][4];   // [gate][k4] input,     K=128 -> 4 MFMA k-steps
    float bias[4];
#pragma unroll
    for (int g = 0; g < 4; ++g) {
        const int row = j * 256 + g * 64 + w * 16 + n;
        bias[g] = bcat[row];
#pragma unroll
        for (int kk = 0; kk < 8; ++kk)
            wh[g][kk] = *(const f16x8*)&Whcat[row * 256 + kk * 32 + q * 8];
#pragma unroll
        for (int k4 = 0; k4 < 4; ++k4)
            wx[g][k4] = *(const f16x8*)&Wxcat[row * ID + k4 * 32 + q * 8];
    }

    float c[4] = {0.f, 0.f, 0.f, 0.f};     // cell state (b = b0+q*4+r, u = uglob)
    const int uglob    = j * 64 + w * 16 + n;
    const int myslot   = (grp * 16 + j * 4 + w) * 64;
    const int pollslot = (grp * 16 + tid) * 64;   // tid<16: producer (j'=tid>>2, w'=tid&3)

    // ---- prefetch x(0) ----
    const float* xrow = &x[(size_t)(b0 + n) * TSEQ * ID];
    float4 xr[8];
#pragma unroll
    for (int k4 = 0; k4 < 4; ++k4) {
        xr[k4 * 2]     = *(const float4*)&xrow[k4 * 32 + q * 8];
        xr[k4 * 2 + 1] = *(const float4*)&xrow[k4 * 32 + q * 8 + 4];
    }

    for (int t = 0; t < TSEQ; ++t) {
        // ---- convert x to fp16 A-fragments, then prefetch x(t+1) ----
        f16x8 xa[4];
#pragma unroll
        for (int k4 = 0; k4 < 4; ++k4) {
            const float* f0 = (const float*)&xr[k4 * 2];
            const float* f1 = (const float*)&xr[k4 * 2 + 1];
#pragma unroll
            for (int e = 0; e < 4; ++e) {
                xa[k4][e]     = (f16)f0[e];
                xa[k4][4 + e] = (f16)f1[e];
            }
        }
        if (t + 1 < TSEQ) {
            const float* xp = &xrow[(size_t)(t + 1) * ID];
#pragma unroll
            for (int k4 = 0; k4 < 4; ++k4) {
                xr[k4 * 2]     = *(const float4*)&xp[k4 * 32 + q * 8];
                xr[k4 * 2 + 1] = *(const float4*)&xp[k4 * 32 + q * 8 + 4];
            }
        }

        // ---- x-projection MFMAs (independent of h — overlaps partners' release) ----
        f32x4 acc[4];
#pragma unroll
        for (int g = 0; g < 4; ++g) {
            f32x4 av = {bias[g], bias[g], bias[g], bias[g]};
            acc[g] = av;
        }
#pragma unroll
        for (int k4 = 0; k4 < 4; ++k4)
#pragma unroll
            for (int g = 0; g < 4; ++g)
                acc[g] = __builtin_amdgcn_mfma_f32_16x16x32_f16(xa[k4], wx[g][k4], acc[g], 0, 0, 0);

        // ---- wait for h(t-1), load A-fragments direct from L3, recurrent MFMAs ----
        if (t > 0) {
            if (tid < 16) {
                while (__hip_atomic_load(&flags[pollslot], __ATOMIC_ACQUIRE,
                                         __HIP_MEMORY_SCOPE_AGENT) < t)
                    __builtin_amdgcn_s_sleep(1);
            }
            __syncthreads();
            const unsigned long long* hp = (const unsigned long long*)
                &hbuf[(size_t)(((t - 1) & 1) * NBATCH + b0 + n) * HD];
            f16x8 ha[8];
#pragma unroll
            for (int kk = 0; kk < 8; ++kk) {
                union { unsigned long long u[2]; f16x8 v; } hu;
                hu.u[0] = __hip_atomic_load(hp + kk * 8 + q * 2,     __ATOMIC_RELAXED,
                                            __HIP_MEMORY_SCOPE_AGENT);
                hu.u[1] = __hip_atomic_load(hp + kk * 8 + q * 2 + 1, __ATOMIC_RELAXED,
                                            __HIP_MEMORY_SCOPE_AGENT);
                ha[kk] = hu.v;
            }
#pragma unroll
            for (int kk = 0; kk < 8; ++kk)
#pragma unroll
                for (int g = 0; g < 4; ++g)
                    acc[g] = __builtin_amdgcn_mfma_f32_16x16x32_f16(ha[kk], wh[g][kk], acc[g], 0, 0, 0);
        }

        // ---- gates, cell/hidden update, publish h ----
#pragma unroll
        for (int r = 0; r < 4; ++r) {
            const float gp_ = acc[0][r], ip_ = acc[1][r], fp_ = acc[2][r], op_ = acc[3][r];
            const float gg = 1.f - 2.f / (1.f + __expf(2.f * gp_));
            const float ii = 1.f / (1.f + __expf(-ip_));
            const float ff = 1.f / (1.f + __expf(-fp_));
            const float oo = 1.f / (1.f + __expf(-op_));
            c[r] = gg * ii + c[r] * ff;
            const float hh = (1.f - 2.f / (1.f + __expf(2.f * c[r]))) * oo;
            const int b = b0 + q * 4 + r;
            if (t < TSEQ - 1) {
                union { _Float16 f; unsigned short s; } cv;
                cv.f = (_Float16)hh;
                __hip_atomic_store((unsigned short*)&hbuf[(size_t)((t & 1) * NBATCH + b) * HD + uglob],
                                   cv.s, __ATOMIC_RELAXED, __HIP_MEMORY_SCOPE_AGENT);
            } else {
                hT[(size_t)b * HD + uglob] = hh;
            }
        }

        // ---- per-wave release: waitcnt before the release store covers all 64
        //      lanes' h stores (wave-level vmcnt). Own 256B line per slot. ----
        if (t < TSEQ - 1) {
            if (lane == 0)
                __hip_atomic_store(&flags[myslot], t + 1, __ATOMIC_RELEASE,
                                   __HIP_MEMORY_SCOPE_AGENT);
        }
    }
}

// ---------------------------------------------------------------------------
// K3: out[b][o] = sum_u hT[b][u] * Wp[o][u] + bp[o]   (fp32)
// ---------------------------------------------------------------------------
__global__ void out_proj(const float* __restrict__ hT, const float* __restrict__ Wp,
                         const float* __restrict__ bp, float* __restrict__ out)
{
    const int b = blockIdx.x;       // 0..255
    const int o = threadIdx.x;      // 0..127
    __shared__ float hrow[HD];
    for (int u = threadIdx.x; u < HD; u += ODIM) hrow[u] = hT[b * HD + u];
    __syncthreads();
    float s = bp[o];
    const float* wr = &Wp[o * HD];
#pragma unroll 8
    for (int u = 0; u < HD; ++u) s += hrow[u] * wr[u];
    out[b * ODIM + o] = s;
}

// ---------------------------------------------------------------------------
extern "C" void kernel_launch(void* const* d_in, const int* in_sizes, int n_in,
                              void* d_out, int out_size, void* d_ws, size_t ws_size,
                              hipStream_t stream) {
    const float* x   = (const float*)d_in[0];
    const float* Wgx = (const float*)d_in[1];
    const float* bgx = (const float*)d_in[2];
    const float* Wgh = (const float*)d_in[3];
    const float* Wix = (const float*)d_in[4];
    const float* bix = (const float*)d_in[5];
    const float* Wih = (const float*)d_in[6];
    const float* Wfx = (const float*)d_in[7];
    const float* bfx = (const float*)d_in[8];
    const float* Wfh = (const float*)d_in[9];
    const float* Wox = (const float*)d_in[10];
    const float* box = (const float*)d_in[11];
    const float* Woh = (const float*)d_in[12];
    const float* Wp  = (const float*)d_in[13];
    const float* bp  = (const float*)d_in[14];
    float* out = (float*)d_out;

    char* ws = (char*)d_ws;
    f16*   Whcat = (f16*)(ws);                         // 1024*256*2    = 524288
    f16*   Wxcat = (f16*)(ws + 524288);                // 1024*128*2    = 262144
    float* bcat  = (float*)(ws + 786432);              // 1024*4        = 4096
    f16*   hbuf  = (f16*)(ws + 790528);                // 2*256*256*2   = 262144
    float* hT    = (float*)(ws + 1052672);             // 256*256*4     = 262144
    int*   flags = (int*)(ws + 1314816);               // 256*64*4      = 65536

    hipMemsetAsync(flags, 0, 256 * 64 * sizeof(int), stream);
    pack_weights<<<1024, 256, 0, stream>>>(Wgh, Wih, Wfh, Woh,
                                           Wgx, Wix, Wfx, Wox,
                                           bgx, bix, bfx, box,
                                           Whcat, Wxcat, bcat);
    lstm_rec<<<64, 256, 0, stream>>>(x, Whcat, Wxcat, bcat, hbuf, hT, flags);
    out_proj<<<NBATCH, ODIM, 0, stream>>>(hT, Wp, bp, out);
}

// Round 3
// 5174.201 us; speedup vs baseline: 1.6379x; 1.3584x over previous
//
#include <hip/hip_runtime.h>
#include <hip/hip_fp16.h>

#define TSEQ 1024
#define NBATCH 256
#define HD 256
#define ID 128
#define ODIM 128

typedef _Float16 f16;
typedef _Float16 f16x8 __attribute__((ext_vector_type(8)));
typedef float f32x4 __attribute__((ext_vector_type(4)));

// ---------------------------------------------------------------------------
// K0: pack recurrent + input weights into fp16, row order n' = j*256 + g*64 + uu
// ---------------------------------------------------------------------------
__global__ void pack_weights(
    const float* __restrict__ Wgh, const float* __restrict__ Wih,
    const float* __restrict__ Wfh, const float* __restrict__ Woh,
    const float* __restrict__ Wgx, const float* __restrict__ Wix,
    const float* __restrict__ Wfx, const float* __restrict__ Wox,
    const float* __restrict__ bgx, const float* __restrict__ bix,
    const float* __restrict__ bfx, const float* __restrict__ box,
    f16* __restrict__ Whcat, f16* __restrict__ Wxcat, float* __restrict__ bcat)
{
    const int np = blockIdx.x;            // 0..1023  (row n')
    const int g  = (np >> 6) & 3;         // gate
    const int j  = np >> 8;               // hidden slice
    const int uu = np & 63;
    const int u  = j * 64 + uu;           // global hidden unit
    const float* Wh = (g == 0) ? Wgh : (g == 1) ? Wih : (g == 2) ? Wfh : Woh;
    const float* Wx = (g == 0) ? Wgx : (g == 1) ? Wix : (g == 2) ? Wfx : Wox;
    const float* bx = (g == 0) ? bgx : (g == 1) ? bix : (g == 2) ? bfx : box;
    const int k = threadIdx.x;            // 0..255
    Whcat[np * 256 + k] = (f16)Wh[u * 256 + k];
    if (k < ID) Wxcat[np * ID + k] = (f16)Wx[u * ID + k];
    if (k == 0) bcat[np] = bx[u];
}

// ---------------------------------------------------------------------------
// K2: persistent fused recurrence.
// 64 WGs x 256 threads. WG = (grp 0..15 [16-batch tile], j 0..3 [64-unit slice]).
// Weights live in registers as MFMA B-fragments. Groups of 4 WGs exchange h
// each step through the IF-cache coherence point using RELAXED agent-scope
// ops only (sc1, no buffer_inv/wbl2 cache maintenance — R2's poll-acquire
// emitted an L2 invalidate per iteration, thrashing every XCD's L2).
// Ordering: producer drains h stores with explicit s_waitcnt vmcnt(0) before
// the relaxed flag store; consumer orders h loads after the poll via
// __syncthreads + control dependence.
// MFMA 16x16x32 f16 layouts:
//   A[m = lane&15][k = (lane>>4)*8 + e]
//   B[n = lane&15][k = (lane>>4)*8 + e]
//   D[m = (lane>>4)*4 + r][n = lane&15]
// ---------------------------------------------------------------------------
__global__ __launch_bounds__(256, 1) void lstm_rec(
    const float* __restrict__ x,
    const f16* __restrict__ Whcat,
    const f16* __restrict__ Wxcat,
    const float* __restrict__ bcat,
    f16* __restrict__ hbuf,     // [2][NBATCH][HD] fp16 parity double-buffer
    float* __restrict__ hT,     // [NBATCH][HD] fp32 final h
    int* __restrict__ flags)    // [256 slots][64 ints]: slot=(grp*16+j*4+w)
{
    const int tid  = threadIdx.x;
    const int lane = tid & 63;
    const int w    = tid >> 6;      // wave 0..3 -> units [w*16, w*16+16)
    const int q    = lane >> 4;
    const int n    = lane & 15;
    const int bid  = blockIdx.x;
    const int grp  = bid >> 2;
    const int j    = bid & 3;
    const int b0   = grp * 16;

    // ---- persistent weight fragments ----
    f16x8 wh[4][8];   // [gate][kk] recurrent, K=256 -> 8 MFMA k-steps
    f16x8 wx[4][4];   // [gate][k4] input,     K=128 -> 4 MFMA k-steps
    float bias[4];
#pragma unroll
    for (int g = 0; g < 4; ++g) {
        const int row = j * 256 + g * 64 + w * 16 + n;
        bias[g] = bcat[row];
#pragma unroll
        for (int kk = 0; kk < 8; ++kk)
            wh[g][kk] = *(const f16x8*)&Whcat[row * 256 + kk * 32 + q * 8];
#pragma unroll
        for (int k4 = 0; k4 < 4; ++k4)
            wx[g][k4] = *(const f16x8*)&Wxcat[row * ID + k4 * 32 + q * 8];
    }

    float c[4] = {0.f, 0.f, 0.f, 0.f};     // cell state (b = b0+q*4+r, u = uglob)
    const int uglob    = j * 64 + w * 16 + n;
    const int myslot   = (grp * 16 + j * 4 + w) * 64;
    const int pollslot = (grp * 16 + tid) * 64;   // tid<16: producer (j'=tid>>2, w'=tid&3)

    // ---- prefetch x(0) ----
    const float* xrow = &x[(size_t)(b0 + n) * TSEQ * ID];
    float4 xr[8];
#pragma unroll
    for (int k4 = 0; k4 < 4; ++k4) {
        xr[k4 * 2]     = *(const float4*)&xrow[k4 * 32 + q * 8];
        xr[k4 * 2 + 1] = *(const float4*)&xrow[k4 * 32 + q * 8 + 4];
    }

    for (int t = 0; t < TSEQ; ++t) {
        // ---- convert x to fp16 A-fragments, then prefetch x(t+1) ----
        f16x8 xa[4];
#pragma unroll
        for (int k4 = 0; k4 < 4; ++k4) {
            const float* f0 = (const float*)&xr[k4 * 2];
            const float* f1 = (const float*)&xr[k4 * 2 + 1];
#pragma unroll
            for (int e = 0; e < 4; ++e) {
                xa[k4][e]     = (f16)f0[e];
                xa[k4][4 + e] = (f16)f1[e];
            }
        }
        if (t + 1 < TSEQ) {
            const float* xp = &xrow[(size_t)(t + 1) * ID];
#pragma unroll
            for (int k4 = 0; k4 < 4; ++k4) {
                xr[k4 * 2]     = *(const float4*)&xp[k4 * 32 + q * 8];
                xr[k4 * 2 + 1] = *(const float4*)&xp[k4 * 32 + q * 8 + 4];
            }
        }

        // ---- x-projection MFMAs (independent of h — overlaps partners' release) ----
        f32x4 acc[4];
#pragma unroll
        for (int g = 0; g < 4; ++g) {
            f32x4 av = {bias[g], bias[g], bias[g], bias[g]};
            acc[g] = av;
        }
#pragma unroll
        for (int k4 = 0; k4 < 4; ++k4)
#pragma unroll
            for (int g = 0; g < 4; ++g)
                acc[g] = __builtin_amdgcn_mfma_f32_16x16x32_f16(xa[k4], wx[g][k4], acc[g], 0, 0, 0);

        // ---- wait for h(t-1): RELAXED poll (no per-iteration buffer_inv) ----
        if (t > 0) {
            if (tid < 16) {
                while (__hip_atomic_load(&flags[pollslot], __ATOMIC_RELAXED,
                                         __HIP_MEMORY_SCOPE_AGENT) < t)
                    __builtin_amdgcn_s_sleep(1);
            }
            __syncthreads();   // orders the h loads below after flag confirmation
            const unsigned long long* hp = (const unsigned long long*)
                &hbuf[(size_t)(((t - 1) & 1) * NBATCH + b0 + n) * HD];
            f16x8 ha[8];
#pragma unroll
            for (int kk = 0; kk < 8; ++kk) {
                union { unsigned long long u[2]; f16x8 v; } hu;
                hu.u[0] = __hip_atomic_load(hp + kk * 8 + q * 2,     __ATOMIC_RELAXED,
                                            __HIP_MEMORY_SCOPE_AGENT);
                hu.u[1] = __hip_atomic_load(hp + kk * 8 + q * 2 + 1, __ATOMIC_RELAXED,
                                            __HIP_MEMORY_SCOPE_AGENT);
                ha[kk] = hu.v;
            }
#pragma unroll
            for (int kk = 0; kk < 8; ++kk)
#pragma unroll
                for (int g = 0; g < 4; ++g)
                    acc[g] = __builtin_amdgcn_mfma_f32_16x16x32_f16(ha[kk], wh[g][kk], acc[g], 0, 0, 0);
        }

        // ---- gates, cell/hidden update, publish h (relaxed, sc1) ----
#pragma unroll
        for (int r = 0; r < 4; ++r) {
            const float gp_ = acc[0][r], ip_ = acc[1][r], fp_ = acc[2][r], op_ = acc[3][r];
            const float gg = 1.f - 2.f / (1.f + __expf(2.f * gp_));
            const float ii = 1.f / (1.f + __expf(-ip_));
            const float ff = 1.f / (1.f + __expf(-fp_));
            const float oo = 1.f / (1.f + __expf(-op_));
            c[r] = gg * ii + c[r] * ff;
            const float hh = (1.f - 2.f / (1.f + __expf(2.f * c[r]))) * oo;
            const int b = b0 + q * 4 + r;
            if (t < TSEQ - 1) {
                union { _Float16 f; unsigned short s; } cv;
                cv.f = (_Float16)hh;
                __hip_atomic_store((unsigned short*)&hbuf[(size_t)((t & 1) * NBATCH + b) * HD + uglob],
                                   cv.s, __ATOMIC_RELAXED, __HIP_MEMORY_SCOPE_AGENT);
            } else {
                hT[(size_t)b * HD + uglob] = hh;
            }
        }

        // ---- manual release: drain this wave's h stores to the coherence
        //      point, then relaxed flag store. No cache-maintenance ops. ----
        if (t < TSEQ - 1) {
            __atomic_signal_fence(__ATOMIC_SEQ_CST);        // no compiler reorder
            __builtin_amdgcn_s_waitcnt(0x0F70);             // vmcnt(0)
            __atomic_signal_fence(__ATOMIC_SEQ_CST);
            if (lane == 0)
                __hip_atomic_store(&flags[myslot], t + 1, __ATOMIC_RELAXED,
                                   __HIP_MEMORY_SCOPE_AGENT);
        }
    }
}

// ---------------------------------------------------------------------------
// K3: out[b][o] = sum_u hT[b][u] * Wp[o][u] + bp[o]   (fp32)
// ---------------------------------------------------------------------------
__global__ void out_proj(const float* __restrict__ hT, const float* __restrict__ Wp,
                         const float* __restrict__ bp, float* __restrict__ out)
{
    const int b = blockIdx.x;       // 0..255
    const int o = threadIdx.x;      // 0..127
    __shared__ float hrow[HD];
    for (int u = threadIdx.x; u < HD; u += ODIM) hrow[u] = hT[b * HD + u];
    __syncthreads();
    float s = bp[o];
    const float* wr = &Wp[o * HD];
#pragma unroll 8
    for (int u = 0; u < HD; ++u) s += hrow[u] * wr[u];
    out[b * ODIM + o] = s;
}

// ---------------------------------------------------------------------------
extern "C" void kernel_launch(void* const* d_in, const int* in_sizes, int n_in,
                              void* d_out, int out_size, void* d_ws, size_t ws_size,
                              hipStream_t stream) {
    const float* x   = (const float*)d_in[0];
    const float* Wgx = (const float*)d_in[1];
    const float* bgx = (const float*)d_in[2];
    const float* Wgh = (const float*)d_in[3];
    const float* Wix = (const float*)d_in[4];
    const float* bix = (const float*)d_in[5];
    const float* Wih = (const float*)d_in[6];
    const float* Wfx = (const float*)d_in[7];
    const float* bfx = (const float*)d_in[8];
    const float* Wfh = (const float*)d_in[9];
    const float* Wox = (const float*)d_in[10];
    const float* box = (const float*)d_in[11];
    const float* Woh = (const float*)d_in[12];
    const float* Wp  = (const float*)d_in[13];
    const float* bp  = (const float*)d_in[14];
    float* out = (float*)d_out;

    char* ws = (char*)d_ws;
    f16*   Whcat = (f16*)(ws);                         // 1024*256*2    = 524288
    f16*   Wxcat = (f16*)(ws + 524288);                // 1024*128*2    = 262144
    float* bcat  = (float*)(ws + 786432);              // 1024*4        = 4096
    f16*   hbuf  = (f16*)(ws + 790528);                // 2*256*256*2   = 262144
    float* hT    = (float*)(ws + 1052672);             // 256*256*4     = 262144
    int*   flags = (int*)(ws + 1314816);               // 256*64*4      = 65536

    hipMemsetAsync(flags, 0, 256 * 64 * sizeof(int), stream);
    pack_weights<<<1024, 256, 0, stream>>>(Wgh, Wih, Wfh, Woh,
                                           Wgx, Wix, Wfx, Wox,
                                           bgx, bix, bfx, box,
                                           Whcat, Wxcat, bcat);
    lstm_rec<<<64, 256, 0, stream>>>(x, Whcat, Wxcat, bcat, hbuf, hT, flags);
    out_proj<<<NBATCH, ODIM, 0, stream>>>(hT, Wp, bp, out);
}